// Round 11
// baseline (246.503 us; speedup 1.0000x reference)
//
#include <hip/hip_runtime.h>
#include <hip/hip_bf16.h>

// ---------------------------------------------------------------------------
// Fused MHA forward on MI355X (gfx950), bf16 MFMA pipeline:
//   1) cast f32->bf16 (activations, weights)
//   2) fused QKV projection GEMM (double-buffered prefetch), epilogue ->
//      head layouts; Q pre-scaled by 0.125*log2(e) (softmax fold)
//   3) flash attention, swapped-QK^T 32x32, KVBLK=128 per barrier interval
//      (2 independent 64-kv sub-tiles -> wide MFMA/VALU scheduling window),
//      tree-reduced softmax, defer-max, P fed to PV from registers.
//   4) output projection GEMM (same dbuf core), fp32 + bias epilogue
// ---------------------------------------------------------------------------

typedef __attribute__((ext_vector_type(8))) short short8;    // 8 x bf16 bits
typedef __attribute__((ext_vector_type(4))) float f32x4;
typedef __attribute__((ext_vector_type(16))) float f32x16;
typedef __attribute__((ext_vector_type(4))) unsigned short us4;

static constexpr int D_MODEL = 1024;
static constexpr int NHEAD   = 16;
static constexpr int DK      = 64;
static constexpr int SEQ     = 2048;
static constexpr int BATCH   = 2;
static constexpr int MTOT    = BATCH * SEQ;   // 4096

// softmax scale folded into Q projection: 1/sqrt(64) * log2(e)
static constexpr float QSCL = 0.125f * 1.44269504088896340736f;

#define DEVINL __device__ __forceinline__

DEVINL unsigned short f2bf(float f) {
    __hip_bfloat16 h = __float2bfloat16(f);   // RNE
    return *reinterpret_cast<unsigned short*>(&h);
}

DEVINL unsigned pack2bf(float lo, float hi) {
    union { __hip_bfloat162 h2; unsigned u; } c;
    float2 f; f.x = lo; f.y = hi;
    c.h2 = __float22bfloat162_rn(f);          // .x -> bits 0-15
    return c.u;
}

// ---------------------------------------------------------------------------
// Cast kernel: up to 4 tensors of identical length, grid.y selects.
// ---------------------------------------------------------------------------
__global__ __launch_bounds__(256) void cast_f32_bf16(
    const float* __restrict__ s0, const float* __restrict__ s1,
    const float* __restrict__ s2, const float* __restrict__ s3,
    unsigned short* __restrict__ d0, unsigned short* __restrict__ d1,
    unsigned short* __restrict__ d2, unsigned short* __restrict__ d3,
    int n)
{
    const float* s; unsigned short* d;
    switch (blockIdx.y) {
        case 0:  s = s0; d = d0; break;
        case 1:  s = s1; d = d1; break;
        case 2:  s = s2; d = d2; break;
        default: s = s3; d = d3; break;
    }
    int i = (blockIdx.x * 256 + threadIdx.x) * 8;
    if (i + 8 > n) return;
    float4 v0 = *reinterpret_cast<const float4*>(s + i);
    float4 v1 = *reinterpret_cast<const float4*>(s + i + 4);
    union { unsigned short u[8]; short8 v; } o;
    o.u[0] = f2bf(v0.x); o.u[1] = f2bf(v0.y); o.u[2] = f2bf(v0.z); o.u[3] = f2bf(v0.w);
    o.u[4] = f2bf(v1.x); o.u[5] = f2bf(v1.y); o.u[6] = f2bf(v1.z); o.u[7] = f2bf(v1.w);
    *reinterpret_cast<short8*>(d + i) = o.v;
}

// ---------------------------------------------------------------------------
// GEMM core (r4-verified): C[m,n] = (A.W^T + bias)*oscale
// 128x128 tile, BK=32, 4 waves, 16x16x32 bf16 MFMA, dbuf prefetch.
// ---------------------------------------------------------------------------
template<int MODE>
DEVINL void gemm_core(const unsigned short* __restrict__ A,
                      const unsigned short* __restrict__ W,
                      const float* __restrict__ bias,
                      void* __restrict__ outp,
                      int m0, int n0, float oscale,
                      unsigned short* a_lds, unsigned short* b_lds) // [2][4096]
{
    constexpr int K = 1024;
    const int tid  = threadIdx.x;
    const int wave = tid >> 6, lane = tid & 63;
    const int wrow = (wave >> 1) * 64, wcol = (wave & 1) * 64;
    const int fr = lane & 15, fg = lane >> 4;

    f32x4 acc[4][4];
    #pragma unroll
    for (int i = 0; i < 4; ++i)
        #pragma unroll
        for (int j = 0; j < 4; ++j)
            acc[i][j] = (f32x4){0.f, 0.f, 0.f, 0.f};

    const int c0 = tid, c1 = tid + 256;
    const unsigned short* gA0 = A + (size_t)(m0 + (c0 >> 2)) * K + (c0 & 3) * 8;
    const unsigned short* gA1 = A + (size_t)(m0 + (c1 >> 2)) * K + (c1 & 3) * 8;
    const unsigned short* gB0 = W + (size_t)(n0 + (c0 >> 2)) * K + (c0 & 3) * 8;
    const unsigned short* gB1 = W + (size_t)(n0 + (c1 >> 2)) * K + (c1 & 3) * 8;
    char* aLb = (char*)a_lds + wave * 1024;
    char* bLb = (char*)b_lds + wave * 1024;

    auto stage = [&](int buf, int kt) {
        const int bo = buf * 8192;
        __builtin_amdgcn_global_load_lds(gA0 + kt * 32, aLb + bo,        16, 0, 0);
        __builtin_amdgcn_global_load_lds(gA1 + kt * 32, aLb + bo + 4096, 16, 0, 0);
        __builtin_amdgcn_global_load_lds(gB0 + kt * 32, bLb + bo,        16, 0, 0);
        __builtin_amdgcn_global_load_lds(gB1 + kt * 32, bLb + bo + 4096, 16, 0, 0);
    };

    stage(0, 0);
    __syncthreads();
    int cur = 0;

    for (int kt = 0; kt < K / 32; ++kt) {
        if (kt + 1 < K / 32) stage(cur ^ 1, kt + 1);

        const unsigned short* aF = a_lds + cur * 4096 + (wrow + fr) * 32 + fg * 8;
        const unsigned short* bF = b_lds + cur * 4096 + (wcol + fr) * 32 + fg * 8;
        short8 af[4], bf[4];
        #pragma unroll
        for (int mt = 0; mt < 4; ++mt)
            af[mt] = *reinterpret_cast<const short8*>(aF + mt * 16 * 32);
        #pragma unroll
        for (int nt = 0; nt < 4; ++nt)
            bf[nt] = *reinterpret_cast<const short8*>(bF + nt * 16 * 32);
        __builtin_amdgcn_s_setprio(1);
        #pragma unroll
        for (int mt = 0; mt < 4; ++mt)
            #pragma unroll
            for (int nt = 0; nt < 4; ++nt)
                acc[mt][nt] = __builtin_amdgcn_mfma_f32_16x16x32_bf16(
                    af[mt], bf[nt], acc[mt][nt], 0, 0, 0);
        __builtin_amdgcn_s_setprio(0);

        __syncthreads();   // drains vmcnt(0): prefetch landed; reads of cur done
        cur ^= 1;
    }

    // epilogue: C/D layout col = lane&15 (=n), row = (lane>>4)*4 + r (=m)
    #pragma unroll
    for (int mt = 0; mt < 4; ++mt) {
        #pragma unroll
        for (int nt = 0; nt < 4; ++nt) {
            f32x4 v = acc[mt][nt];
            const int n = n0 + wcol + nt * 16 + fr;
            const float bi = bias[n];
            if constexpr (MODE == 2) {
                #pragma unroll
                for (int r = 0; r < 4; ++r) {
                    const int m = m0 + wrow + mt * 16 + fg * 4 + r;
                    ((float*)outp)[(size_t)m * D_MODEL + n] = (v[r] + bi) * oscale;
                }
            } else if constexpr (MODE == 0) {
                #pragma unroll
                for (int r = 0; r < 4; ++r) {
                    const int m = m0 + wrow + mt * 16 + fg * 4 + r;
                    const int b = m >> 11, s = m & 2047;
                    const int h = n >> 6,  d = n & 63;
                    ((unsigned short*)outp)[((size_t)(b * NHEAD + h) * SEQ + s) * DK + d]
                        = f2bf((v[r] + bi) * oscale);
                }
            } else {   // MODE 1: vT [B,H,DK,S], 4 consecutive s -> 8B store
                const int sbase = m0 + wrow + mt * 16 + fg * 4;
                const int b = sbase >> 11, s = sbase & 2047;
                const int h = n >> 6, d = n & 63;
                us4 pk;
                #pragma unroll
                for (int r = 0; r < 4; ++r)
                    pk[r] = f2bf((v[r] + bi) * oscale);
                *reinterpret_cast<us4*>(
                    (unsigned short*)outp
                    + ((size_t)(b * NHEAD + h) * DK + d) * SEQ + s) = pk;
            }
        }
    }
}

__global__ __launch_bounds__(256) void qkv_gemm(
    const unsigned short* __restrict__ Qb, const unsigned short* __restrict__ Kb,
    const unsigned short* __restrict__ Vb,
    const unsigned short* __restrict__ Wq, const unsigned short* __restrict__ Wk,
    const unsigned short* __restrict__ Wv,
    const float* __restrict__ bq, const float* __restrict__ bk,
    const float* __restrict__ bv,
    unsigned short* __restrict__ qh, unsigned short* __restrict__ kh,
    unsigned short* __restrict__ vT)
{
    __shared__ unsigned short a_lds[2 * 128 * 32];
    __shared__ unsigned short b_lds[2 * 128 * 32];
    const int sel = blockIdx.y >> 3;
    const int n0  = (blockIdx.y & 7) * 128;
    const int m0  = blockIdx.x * 128;
    if (sel == 0)      gemm_core<0>(Qb, Wq, bq, qh, m0, n0, QSCL, a_lds, b_lds);
    else if (sel == 1) gemm_core<0>(Kb, Wk, bk, kh, m0, n0, 1.0f, a_lds, b_lds);
    else               gemm_core<1>(Vb, Wv, bv, vT, m0, n0, 1.0f, a_lds, b_lds);
}

__global__ __launch_bounds__(256) void oproj_gemm(
    const unsigned short* __restrict__ ctx, const unsigned short* __restrict__ Wo,
    const float* __restrict__ bo, float* __restrict__ out)
{
    __shared__ unsigned short a_lds[2 * 128 * 32];
    __shared__ unsigned short b_lds[2 * 128 * 32];
    gemm_core<2>(ctx, Wo, bo, out, blockIdx.x * 128, blockIdx.y * 128, 1.0f,
                 a_lds, b_lds);
}

// ---------------------------------------------------------------------------
// Flash attention, swapped-QK^T 32x32, KVBLK=128 per interval.
// grid (S/128, H, B), 256 thr (4 waves); wave owns 32 q-rows.
// Per barrier interval: stage NEXT 128 kv (8 gload_lds/thread), then process
// TWO independent 64-kv sub-tiles (S^T 16 mfma, combined 64-val tree max,
// one defer check, 64 exp2 + tree sums, pack, PV 16 mfma). One barrier per
// 128 kv. Layouts identical to the r7-verified kernel.
// ---------------------------------------------------------------------------
__global__ __launch_bounds__(256) void attn_fwd(
    const unsigned short* __restrict__ qh,
    const unsigned short* __restrict__ kh,
    const unsigned short* __restrict__ vT,
    unsigned short* __restrict__ ctx)
{
    __shared__ unsigned short k_lds[2][2][64 * 64];   // [buf][subtile] 32 KiB
    __shared__ unsigned short v_lds[2][2][64 * 64];   // 32 KiB

    const int tid  = threadIdx.x;
    const int wave = tid >> 6, lane = tid & 63;
    const int q    = lane & 31, hi = lane >> 5;
    const int h = blockIdx.y, b = blockIdx.z;
    const int q0 = blockIdx.x * 128 + wave * 32;

    const size_t headoff = (size_t)(b * NHEAD + h) * SEQ * DK;
    const unsigned short* qbase = qh + headoff;
    const unsigned short* kbase = kh + headoff;
    const unsigned short* vbase = vT + headoff;   // [DK][SEQ]

    // Q as B-operand: row n=q, k-group hi*8; call c covers d = c*16..+16
    short8 qf[4];
    #pragma unroll
    for (int c = 0; c < 4; ++c)
        qf[c] = *reinterpret_cast<const short8*>(
            qbase + (size_t)(q0 + q) * DK + c * 16 + hi * 8);

    // staging (r7-verified mapping within each 8KB sub-tile):
    // chunk c -> lds byte c*16; row=c>>3, src slot=(c&7)^(row&7)
    const int c0 = tid, c1 = 256 + tid;
    const int r0 = c0 >> 3, s0i = (c0 & 7) ^ (r0 & 7);
    const int r1 = c1 >> 3, s1i = (c1 & 7) ^ (r1 & 7);
    const unsigned short* gk0 = kbase + (size_t)r0 * DK + s0i * 8;
    const unsigned short* gk1 = kbase + (size_t)r1 * DK + s1i * 8;
    const unsigned short* gv0 = vbase + (size_t)r0 * SEQ + s0i * 8;
    const unsigned short* gv1 = vbase + (size_t)r1 * SEQ + s1i * 8;

    auto stage = [&](int buf, int kv0) {   // kv0 multiple of 128
        #pragma unroll
        for (int st = 0; st < 2; ++st) {
            char* kb = (char*)k_lds[buf][st] + wave * 1024;
            char* vb = (char*)v_lds[buf][st] + wave * 1024;
            const int kvs = kv0 + st * 64;
            __builtin_amdgcn_global_load_lds(gk0 + (size_t)kvs * DK, kb,        16, 0, 0);
            __builtin_amdgcn_global_load_lds(gk1 + (size_t)kvs * DK, kb + 4096, 16, 0, 0);
            __builtin_amdgcn_global_load_lds(gv0 + kvs,              vb,        16, 0, 0);
            __builtin_amdgcn_global_load_lds(gv1 + kvs,              vb + 4096, 16, 0, 0);
        }
    };

    f32x16 oacc[2];
    #pragma unroll
    for (int kd = 0; kd < 2; ++kd)
        #pragma unroll
        for (int r = 0; r < 16; ++r) oacc[kd][r] = 0.f;
    float mrun = -1e30f, lpart = 0.f;
    constexpr float THR = 8.0f;

    stage(0, 0);
    __syncthreads();
    int cur = 0;

    for (int kt = 0; kt < SEQ / 128; ++kt) {
        if (kt + 1 < SEQ / 128) stage(cur ^ 1, (kt + 1) * 128);

        // ---- S^T for both sub-tiles: sacc[st*2+kb] over 4 d-slices
        f32x16 sacc[4];
        #pragma unroll
        for (int sb = 0; sb < 4; ++sb)
            #pragma unroll
            for (int r = 0; r < 16; ++r) sacc[sb][r] = 0.f;

        __builtin_amdgcn_s_setprio(1);
        #pragma unroll
        for (int st = 0; st < 2; ++st) {
            const char* kl = (const char*)k_lds[cur][st];
            #pragma unroll
            for (int kb = 0; kb < 2; ++kb) {
                const int krow = kb * 32 + q;
                const int ksw  = (krow & 7) << 4;
                #pragma unroll
                for (int c = 0; c < 4; ++c) {
                    short8 kf = *reinterpret_cast<const short8*>(
                        kl + krow * 128 + ((c * 32 + hi * 16) ^ ksw));
                    sacc[st * 2 + kb] = __builtin_amdgcn_mfma_f32_32x32x16_bf16(
                        kf, qf[c], sacc[st * 2 + kb], 0, 0, 0);
                }
            }
        }
        __builtin_amdgcn_s_setprio(0);

        // ---- combined 64-value tree max (depth ~5, full ILP)
        float t8[8];
        #pragma unroll
        for (int j = 0; j < 8; ++j) {
            const float a = fmaxf(sacc[0][j], sacc[0][j + 8]);
            const float bb = fmaxf(sacc[1][j], sacc[1][j + 8]);
            const float cc = fmaxf(sacc[2][j], sacc[2][j + 8]);
            const float dd = fmaxf(sacc[3][j], sacc[3][j + 8]);
            t8[j] = fmaxf(fmaxf(a, bb), fmaxf(cc, dd));
        }
        float pm = fmaxf(fmaxf(fmaxf(t8[0], t8[1]), fmaxf(t8[2], t8[3])),
                         fmaxf(fmaxf(t8[4], t8[5]), fmaxf(t8[6], t8[7])));
        pm = fmaxf(pm, __shfl_xor(pm, 32));

        // defer-max: one check per 128 kv
        if (__any(pm > mrun + THR)) {
            const float mx = fmaxf(pm, mrun);
            const float alpha = __builtin_amdgcn_exp2f(mrun - mx);
            mrun = mx;
            lpart *= alpha;
            #pragma unroll
            for (int kd = 0; kd < 2; ++kd)
                #pragma unroll
                for (int r = 0; r < 16; ++r) oacc[kd][r] *= alpha;
        }

        // ---- P = exp2(S - m); 4-way partial sums (tree)
        float psum[4] = {0.f, 0.f, 0.f, 0.f};
        #pragma unroll
        for (int sb = 0; sb < 4; ++sb)
            #pragma unroll
            for (int r = 0; r < 16; ++r) {
                const float p = __builtin_amdgcn_exp2f(sacc[sb][r] - mrun);
                sacc[sb][r] = p;
                psum[r & 3] += p;
            }
        float ps = (psum[0] + psum[1]) + (psum[2] + psum[3]);
        ps += __shfl_xor(ps, 32);
        lpart += ps;

        // ---- pack P to bf16 pairs
        unsigned w[4][8];
        #pragma unroll
        for (int sb = 0; sb < 4; ++sb)
            #pragma unroll
            for (int m = 0; m < 8; ++m)
                w[sb][m] = pack2bf(sacc[sb][2 * m], sacc[sb][2 * m + 1]);

        // ---- O^T += V^T . P  (both sub-tiles)
        #pragma unroll
        for (int st = 0; st < 2; ++st) {
            const char* vl = (const char*)v_lds[cur][st];
            #pragma unroll
            for (int kb = 0; kb < 2; ++kb) {
                #pragma unroll
                for (int kc = 0; kc < 2; ++kc) {
                    const int sb = st * 2 + kb;
                    const unsigned o0 = hi ? w[sb][4 * kc + 2] : w[sb][4 * kc + 0];
                    const unsigned o1 = hi ? w[sb][4 * kc + 3] : w[sb][4 * kc + 1];
                    const unsigned sp0 = hi ? w[sb][4 * kc + 0] : w[sb][4 * kc + 2];
                    const unsigned sp1 = hi ? w[sb][4 * kc + 1] : w[sb][4 * kc + 3];
                    const unsigned e0 = (unsigned)__shfl_xor((int)sp0, 32);
                    const unsigned e1 = (unsigned)__shfl_xor((int)sp1, 32);
                    union { unsigned u[4]; short8 v; } pf;
                    pf.u[0] = hi ? e0 : o0;
                    pf.u[1] = hi ? e1 : o1;
                    pf.u[2] = hi ? o0 : e0;
                    pf.u[3] = hi ? o1 : e1;

                    __builtin_amdgcn_s_setprio(1);
                    #pragma unroll
                    for (int kd = 0; kd < 2; ++kd) {
                        const int vrow = kd * 32 + q;
                        const int slot = kb * 4 + kc * 2 + hi;   // 16B col chunk
                        short8 vf = *reinterpret_cast<const short8*>(
                            vl + vrow * 128 + ((slot * 16) ^ ((vrow & 7) << 4)));
                        oacc[kd] = __builtin_amdgcn_mfma_f32_32x32x16_bf16(
                            vf, pf.v, oacc[kd], 0, 0, 0);
                    }
                    __builtin_amdgcn_s_setprio(0);
                }
            }
        }

        __syncthreads();   // all waves done with buf cur; prefetch landed
        cur ^= 1;
    }

    // finalize: lane-scalar normalize; store 4-elem bf16 runs (8B stores)
    const float inv = 1.f / lpart;
    unsigned short* crow = ctx + ((size_t)(b * SEQ + q0 + q)) * D_MODEL + h * DK;
    #pragma unroll
    for (int kd = 0; kd < 2; ++kd)
        #pragma unroll
        for (int rr = 0; rr < 4; ++rr) {
            us4 pk;
            #pragma unroll
            for (int e = 0; e < 4; ++e)
                pk[e] = f2bf(oacc[kd][rr * 4 + e] * inv);
            // D row = (r&3)+8*(r>>2)+4*hi -> d = kd*32 + rr*8 + hi*4 + e
            *reinterpret_cast<us4*>(crow + kd * 32 + rr * 8 + hi * 4) = pk;
        }
}

// ---------------------------------------------------------------------------
extern "C" void kernel_launch(void* const* d_in, const int* in_sizes, int n_in,
                              void* d_out, int out_size, void* d_ws, size_t ws_size,
                              hipStream_t stream)
{
    const float* Q  = (const float*)d_in[0];
    const float* K  = (const float*)d_in[1];
    const float* V  = (const float*)d_in[2];
    const float* Wq = (const float*)d_in[3];
    const float* bq = (const float*)d_in[4];
    const float* Wk = (const float*)d_in[5];
    const float* bk = (const float*)d_in[6];
    const float* Wv = (const float*)d_in[7];
    const float* bv = (const float*)d_in[8];
    const float* Wo = (const float*)d_in[9];
    const float* bo = (const float*)d_in[10];

    char* ws = (char*)d_ws;
    const size_t SZ_ACT = (size_t)MTOT * D_MODEL * 2;      // 8 MiB
    const size_t SZ_W   = (size_t)D_MODEL * D_MODEL * 2;   // 2 MiB
    unsigned short* Qb  = (unsigned short*)(ws);
    unsigned short* Kb  = (unsigned short*)(ws + SZ_ACT);
    unsigned short* Vb  = (unsigned short*)(ws + 2 * SZ_ACT);
    unsigned short* Wqb = (unsigned short*)(ws + 3 * SZ_ACT);
    unsigned short* Wkb = (unsigned short*)(ws + 3 * SZ_ACT + SZ_W);
    unsigned short* Wvb = (unsigned short*)(ws + 3 * SZ_ACT + 2 * SZ_W);
    unsigned short* Wob = (unsigned short*)(ws + 3 * SZ_ACT + 3 * SZ_W);
    unsigned short* qhd = (unsigned short*)(ws + 3 * SZ_ACT + 4 * SZ_W);
    unsigned short* khd = (unsigned short*)(ws + 4 * SZ_ACT + 4 * SZ_W);
    unsigned short* vTd = (unsigned short*)(ws + 5 * SZ_ACT + 4 * SZ_W);
    unsigned short* ctx = (unsigned short*)(ws + 6 * SZ_ACT + 4 * SZ_W);

    const int nAct = MTOT * D_MODEL;        // 4194304
    const int nW   = D_MODEL * D_MODEL;     // 1048576

    cast_f32_bf16<<<dim3(nAct / (256 * 8), 3), 256, 0, stream>>>(
        Q, K, V, nullptr, Qb, Kb, Vb, nullptr, nAct);
    cast_f32_bf16<<<dim3(nW / (256 * 8), 4), 256, 0, stream>>>(
        Wq, Wk, Wv, Wo, Wqb, Wkb, Wvb, Wob, nW);

    qkv_gemm<<<dim3(MTOT / 128, 24), 256, 0, stream>>>(
        Qb, Kb, Vb, Wqb, Wkb, Wvb, bq, bk, bv, qhd, khd, vTd);

    attn_fwd<<<dim3(SEQ / 128, NHEAD, BATCH), 256, 0, stream>>>(
        qhd, khd, vTd, ctx);

    oproj_gemm<<<dim3(MTOT / 128, D_MODEL / 128), 256, 0, stream>>>(
        ctx, Wob, bo, (float*)d_out);
}